// Round 8
// baseline (259.135 us; speedup 1.0000x reference)
//
#include <hip/hip_runtime.h>
#include <hip/hip_bf16.h>
#include <stdint.h>

#define BATCH    512
#define IN_DIM   256
#define OUT_DIM  256
#define COND_DIM 128
#define HIDDEN   128
#define W2_COLS  65792      // 256*257
#define H_STRIDE 132
#define PLANE_SZ 65536      // shorts per frag-ordered plane [nt][kb][lane][8]
#define NCHUNKS  34         // 32x4-plane + {b2,bw} + bias
#define OUT_ELEMS (BATCH * OUT_DIM)
#define SLICE_OFF ((size_t)131 * PLANE_SZ)   // shorts: slices after 131 planes

typedef __attribute__((ext_vector_type(8))) short bf16x8;
typedef __attribute__((ext_vector_type(4))) float f32x4;

__device__ float          g_h[BATCH * H_STRIDE + 8];   // f32 h (+1.0 lanes), padded
__device__ unsigned short g_hbf[BATCH * HIDDEN];       // bf16 h rows (bias-chunk A)
__device__ unsigned short g_xbf[BATCH * IN_DIM];       // bf16 x rows (A)

// round-half-up bf16: 2 v-ops; pack2: 3 v-ops via v_perm_b32
static __device__ __forceinline__ unsigned int fbits(float f) {
    union { float f; unsigned int u; } v; v.f = f; return v.u;
}
static __device__ __forceinline__ unsigned short f2bf(float f) {
    return (unsigned short)((fbits(f) + 0x8000u) >> 16);
}
static __device__ __forceinline__ unsigned int pack2(float a, float b) {
    return __builtin_amdgcn_perm(fbits(b) + 0x8000u, fbits(a) + 0x8000u, 0x07060302u);
}
static __device__ __forceinline__ float bf2f(unsigned short u) {
    union { unsigned int u; float f; } v; v.u = ((unsigned int)u) << 16;
    return v.f;
}

// ---------------- prep: pack planes into MFMA-B-fragment order ------------
// Frag layout: wt[((p*16 + nt)*8 + kb)*512 + lane*8 + j] (shorts)
//   element (o = nt*16 + (lane&15), i = kb*32 + (lane>>4)*8 + j)
// Block tiling: (plane, 16-i slab). Thread t -> o = t (one column), 16 i's.
// grid: [0,2080) planes 0..129; [2080,2088) plane 130 (bias cols);
//       [2088,2104) x convert; [2104,2360) h compute (2 rows/block)
// Block 0 also zeroes the 32 per-tile split-K counters (stream-ordered
// before main, so no extra memset node is needed).
__global__ __launch_bounds__(256)
void hyper_prep_kernel(const float* __restrict__ x,
                       const float* __restrict__ cond,
                       const float* __restrict__ base_weight,
                       const float* __restrict__ w1,
                       const float* __restrict__ b1,
                       const float* __restrict__ w2,
                       const float* __restrict__ b2,
                       unsigned short* __restrict__ wt) {
    const int bx = blockIdx.x;
    const int t  = threadIdx.x;
    if (bx == 0 && t < 32) {
        int* counters = (int*)(wt + SLICE_OFF + (size_t)NCHUNKS * OUT_ELEMS);
        counters[t] = 0;
    }
    if (bx < 2088) {
        int p, i0; const float* src; size_t rstride;
        if (bx < 2080) {
            p  = bx >> 4;
            i0 = (bx & 15) * 16;
            src = (p < 128) ? (w2 + (size_t)p * W2_COLS)
                            : (p == 128 ? b2 : base_weight);
            rstride = OUT_DIM;
        } else {
            p  = 130;
            i0 = (bx - 2080) * 16;            // i < 128
            src = w2 + 65536; rstride = W2_COLS;
        }
        const int o = t;                      // 0..255
        const float* s = src + (size_t)i0 * rstride + o;
        float f[16];
        #pragma unroll
        for (int j = 0; j < 16; ++j) f[j] = s[(size_t)j * rstride];

        const int nt = o >> 4, kb = i0 >> 5, iq0 = (i0 >> 3) & 3;
        unsigned short* pbase = wt + ((size_t)(p * 16 + nt) * 8 + kb) * 512;
        unsigned int v0[4], v1[4];
        #pragma unroll
        for (int q = 0; q < 4; ++q) {
            v0[q] = pack2(f[q * 2],     f[q * 2 + 1]);
            v1[q] = pack2(f[8 + q * 2], f[8 + q * 2 + 1]);
        }
        *(uint4*)(pbase + ((size_t)(iq0       * 16 + (o & 15))) * 8) = *(uint4*)v0;
        *(uint4*)(pbase + ((size_t)((iq0 + 1) * 16 + (o & 15))) * 8) = *(uint4*)v1;
    } else if (bx < 2104) {
        int base = (bx - 2088) * 8192 + t * 32;
        #pragma unroll
        for (int g = 0; g < 4; ++g) {
            const float4* s4 = (const float4*)(x + base + g * 8);
            float4 a = s4[0], b = s4[1];
            unsigned int vv[4] = { pack2(a.x, a.y), pack2(a.z, a.w),
                                   pack2(b.x, b.y), pack2(b.z, b.w) };
            *(uint4*)(g_xbf + base + g * 8) = *(uint4*)vv;
        }
    } else if (bx >= 2104) {
        __shared__ float c[2][COND_DIM];
        int bb = t >> 7, k = t & 127;
        int b  = (bx - 2104) * 2 + bb;
        c[bb][k] = cond[b * COND_DIM + k];
        __syncthreads();
        float acc = b1[k];
        #pragma unroll 8
        for (int i = 0; i < COND_DIM; ++i)
            acc += c[bb][i] * w1[i * HIDDEN + k];
        acc = fmaxf(acc, 0.0f);
        g_h[b * H_STRIDE + k] = acc;
        g_hbf[b * HIDDEN + k] = f2bf(acc);
        if (k < 4) g_h[b * H_STRIDE + 128 + k] = 1.0f;
    }
}

// ---------------- main: register-resident GEMM, linear B-frag loads -------
// Block: 64x64 out tile, 4 waves 2x2. A frags in VGPR (loaded once).
// Per plane: 4*NSL linear 1KB global loads (B frags) + 4*NSL MFMA, no barrier.
// Split-K fused reduction: last block per tile sums the 34 bf16 slices.
template<int NPL, int NSL>
static __device__ __forceinline__ void run_gemm(
    int p0, const unsigned short* __restrict__ asrc, int astride,
    const unsigned short* __restrict__ wt, unsigned short* __restrict__ slices,
    int chunk, int b0, int o0, int t, const float* __restrict__ h_s)
{
    const int lane = t & 63, wave = t >> 6;
    const int wm = wave >> 1, wn = wave & 1;
    const int qg = lane >> 4, ncol = lane & 15;

    // A fragments (registers, whole block's K)
    bf16x8 xf[NSL][2][2];
    #pragma unroll
    for (int sl = 0; sl < NSL; ++sl)
        #pragma unroll
        for (int ks = 0; ks < 2; ++ks)
            #pragma unroll
            for (int mf = 0; mf < 2; ++mf)
                xf[sl][ks][mf] = *(const bf16x8*)(asrc
                    + (size_t)(b0 + wm * 32 + mf * 16 + ncol) * astride
                    + sl * 64 + ks * 32 + qg * 8);

    // B frag base: this wave's first ntile, lane-linear 16B
    const unsigned short* fb = wt
        + ((size_t)(p0 * 16 + (o0 >> 4) + wn * 2) * 8) * 512 + (size_t)lane * 8;

    f32x4 acc[2][2] = {};

    #pragma unroll
    for (int pl = 0; pl < NPL; ++pl) {
        bf16x8 bfr[NSL][2][2];
        #pragma unroll
        for (int sl = 0; sl < NSL; ++sl)
            #pragma unroll
            for (int ks = 0; ks < 2; ++ks)
                #pragma unroll
                for (int nf = 0; nf < 2; ++nf)
                    bfr[sl][ks][nf] = *(const bf16x8*)(fb + (size_t)pl * PLANE_SZ
                        + (size_t)(nf * 8 + sl * 2 + ks) * 512);

        float hv[2][4];
        #pragma unroll
        for (int mf = 0; mf < 2; ++mf)
            #pragma unroll
            for (int r = 0; r < 4; ++r)
                hv[mf][r] = h_s[(wm * 32 + mf * 16 + qg * 4 + r) * 4 + pl];

        f32x4 pacc[2][2] = {};
        #pragma unroll
        for (int sl = 0; sl < NSL; ++sl)
            #pragma unroll
            for (int ks = 0; ks < 2; ++ks)
                #pragma unroll
                for (int mf = 0; mf < 2; ++mf)
                    #pragma unroll
                    for (int nf = 0; nf < 2; ++nf)
                        pacc[mf][nf] = __builtin_amdgcn_mfma_f32_16x16x32_bf16(
                            xf[sl][ks][mf], bfr[sl][ks][nf], pacc[mf][nf], 0, 0, 0);

        #pragma unroll
        for (int mf = 0; mf < 2; ++mf)
            #pragma unroll
            for (int nf = 0; nf < 2; ++nf)
                #pragma unroll
                for (int r = 0; r < 4; ++r)
                    acc[mf][nf][r] += hv[mf][r] * pacc[mf][nf][r];
    }

    // epilogue: bf16 slice. C/D layout: col=lane&15, row=qg*4+reg
    unsigned short* slice = slices + (size_t)chunk * OUT_ELEMS;
    #pragma unroll
    for (int mf = 0; mf < 2; ++mf)
        #pragma unroll
        for (int nf = 0; nf < 2; ++nf)
            #pragma unroll
            for (int r = 0; r < 4; ++r) {
                int row = b0 + wm * 32 + mf * 16 + qg * 4 + r;
                int col = o0 + wn * 32 + nf * 16 + ncol;
                slice[(size_t)row * OUT_DIM + col] = f2bf(acc[mf][nf][r]);
            }
}

__global__ __launch_bounds__(256, 2)
void hyper_main_kernel(const unsigned short* __restrict__ wt,
                       unsigned short* __restrict__ slices,
                       const float* __restrict__ base_bias,
                       const float* __restrict__ b2,
                       float* __restrict__ out) {
    __shared__ float h_s[256];
    __shared__ int s_last;

    const int bx    = blockIdx.x;            // 34 * 32
    const int chunk = bx >> 5;
    const int rem   = bx & 31;
    const int b0    = (rem >> 2) * 64;
    const int o0    = (rem & 3) * 64;
    const int t     = threadIdx.x;

    const int p0 = (chunk < 32) ? chunk * 4 : (chunk == 32 ? 128 : 130);

    h_s[t] = g_h[(b0 + (t >> 2)) * H_STRIDE + p0 + (t & 3)];
    __syncthreads();

    if (chunk < 32)
        run_gemm<4, 4>(p0, g_xbf, IN_DIM, wt, slices, chunk, b0, o0, t, h_s);
    else if (chunk == 32)
        run_gemm<2, 4>(p0, g_xbf, IN_DIM, wt, slices, chunk, b0, o0, t, h_s);
    else
        run_gemm<1, 2>(p0, g_hbf, HIDDEN, wt, slices, chunk, b0, o0, t, h_s);

    // ---- split-K handshake: 34th arrival for this tile reduces it --------
    __threadfence();                         // release slice stores (device scope)
    if (t == 0) {
        int* counters = (int*)(slices + (size_t)NCHUNKS * OUT_ELEMS);
        s_last = (atomicAdd(&counters[rem], 1) == NCHUNKS - 1);
    }
    __syncthreads();
    if (!s_last) return;
    __threadfence();                         // acquire before reading peers' slices

    // reduce this 64x64 tile: thread t -> row r = t>>2, cols c0..c0+15
    const int r  = t >> 2;
    const int c0 = (t & 3) * 16;
    float a[16];
    {
        const float* bb = base_bias + o0 + c0;
        const float* cb = b2 + 65536 + o0 + c0;
        #pragma unroll
        for (int j = 0; j < 16; ++j) a[j] = bb[j] + cb[j];
    }
    #pragma unroll 4
    for (int c = 0; c < NCHUNKS; ++c) {
        const unsigned short* sp = slices + (size_t)c * OUT_ELEMS
            + (size_t)(b0 + r) * OUT_DIM + o0 + c0;
        uint4 v0 = *(const uint4*)sp;
        uint4 v1 = *(const uint4*)(sp + 8);
        const unsigned short* u0 = (const unsigned short*)&v0;
        const unsigned short* u1 = (const unsigned short*)&v1;
        #pragma unroll
        for (int j = 0; j < 8; ++j) a[j]     += bf2f(u0[j]);
        #pragma unroll
        for (int j = 0; j < 8; ++j) a[8 + j] += bf2f(u1[j]);
    }
    float* op = out + (size_t)(b0 + r) * OUT_DIM + o0 + c0;
    #pragma unroll
    for (int q = 0; q < 4; ++q)
        *(float4*)(op + q * 4) = (float4){a[q * 4], a[q * 4 + 1],
                                          a[q * 4 + 2], a[q * 4 + 3]};
}

// ---------------- launch ---------------------------------------------------
extern "C" void kernel_launch(void* const* d_in, const int* in_sizes, int n_in,
                              void* d_out, int out_size, void* d_ws, size_t ws_size,
                              hipStream_t stream) {
    const float* x           = (const float*)d_in[0];
    const float* cond        = (const float*)d_in[1];
    const float* base_weight = (const float*)d_in[2];
    const float* base_bias   = (const float*)d_in[3];
    const float* w1          = (const float*)d_in[4];
    const float* b1          = (const float*)d_in[5];
    const float* w2          = (const float*)d_in[6];
    const float* b2          = (const float*)d_in[7];
    float* out = (float*)d_out;
    unsigned short* ws = (unsigned short*)d_ws;  // 131 frag-planes + 34 slices + 32 counters

    hyper_prep_kernel<<<2360, 256, 0, stream>>>(x, cond, base_weight, w1, b1, w2, b2, ws);
    hyper_main_kernel<<<NCHUNKS * 32, 256, 0, stream>>>(ws, ws + SLICE_OFF, base_bias, b2, out);
}

// Round 9
// 126.748 us; speedup vs baseline: 2.0445x; 2.0445x over previous
//
#include <hip/hip_runtime.h>
#include <hip/hip_bf16.h>
#include <stdint.h>

#define BATCH    512
#define IN_DIM   256
#define OUT_DIM  256
#define COND_DIM 128
#define HIDDEN   128
#define W2_COLS  65792      // 256*257
#define H_STRIDE 132
#define PLANE_SZ 65536      // shorts per frag-ordered plane [nt][kb][lane][8]
#define NCHUNKS  34         // 32x4-plane + {b2,bw} + bias
#define OUT_ELEMS (BATCH * OUT_DIM)
#define SLICE_OFF ((size_t)131 * PLANE_SZ)   // shorts: slices after 131 planes

typedef __attribute__((ext_vector_type(8))) short bf16x8;
typedef __attribute__((ext_vector_type(4))) float f32x4;

__device__ float          g_h[BATCH * H_STRIDE + 8];   // f32 h (+1.0 lanes), padded
__device__ unsigned short g_hbf[BATCH * HIDDEN];       // bf16 h rows (bias-chunk A)
__device__ unsigned short g_xbf[BATCH * IN_DIM];       // bf16 x rows (A)

// round-half-up bf16: 2 v-ops; pack2: 3 v-ops via v_perm_b32
static __device__ __forceinline__ unsigned int fbits(float f) {
    union { float f; unsigned int u; } v; v.f = f; return v.u;
}
static __device__ __forceinline__ unsigned short f2bf(float f) {
    return (unsigned short)((fbits(f) + 0x8000u) >> 16);
}
static __device__ __forceinline__ unsigned int pack2(float a, float b) {
    return __builtin_amdgcn_perm(fbits(b) + 0x8000u, fbits(a) + 0x8000u, 0x07060302u);
}
static __device__ __forceinline__ float bf2f(unsigned short u) {
    union { unsigned int u; float f; } v; v.u = ((unsigned int)u) << 16;
    return v.f;
}

// ---------------- prep: pack planes into MFMA-B-fragment order ------------
// Frag layout: wt[((p*16 + nt)*8 + kb)*512 + lane*8 + j] (shorts)
//   element (o = nt*16 + (lane&15), i = kb*32 + (lane>>4)*8 + j)
// Block tiling: (plane, 16-i slab). Thread t -> o = t (one column), 16 i's.
// grid: [0,2080) planes 0..129; [2080,2088) plane 130 (bias cols);
//       [2088,2104) x convert; [2104,2360) h compute (2 rows/block)
__global__ __launch_bounds__(256)
void hyper_prep_kernel(const float* __restrict__ x,
                       const float* __restrict__ cond,
                       const float* __restrict__ base_weight,
                       const float* __restrict__ w1,
                       const float* __restrict__ b1,
                       const float* __restrict__ w2,
                       const float* __restrict__ b2,
                       unsigned short* __restrict__ wt) {
    const int bx = blockIdx.x;
    const int t  = threadIdx.x;
    if (bx < 2088) {
        int p, i0; const float* src; size_t rstride;
        if (bx < 2080) {
            p  = bx >> 4;
            i0 = (bx & 15) * 16;
            src = (p < 128) ? (w2 + (size_t)p * W2_COLS)
                            : (p == 128 ? b2 : base_weight);
            rstride = OUT_DIM;
        } else {
            p  = 130;
            i0 = (bx - 2080) * 16;            // i < 128
            src = w2 + 65536; rstride = W2_COLS;
        }
        const int o = t;                      // 0..255
        const float* s = src + (size_t)i0 * rstride + o;
        float f[16];
        #pragma unroll
        for (int j = 0; j < 16; ++j) f[j] = s[(size_t)j * rstride];

        const int nt = o >> 4, kb = i0 >> 5, iq0 = (i0 >> 3) & 3;
        unsigned short* pbase = wt + ((size_t)(p * 16 + nt) * 8 + kb) * 512;
        unsigned int v0[4], v1[4];
        #pragma unroll
        for (int q = 0; q < 4; ++q) {
            v0[q] = pack2(f[q * 2],     f[q * 2 + 1]);
            v1[q] = pack2(f[8 + q * 2], f[8 + q * 2 + 1]);
        }
        *(uint4*)(pbase + ((size_t)(iq0       * 16 + (o & 15))) * 8) = *(uint4*)v0;
        *(uint4*)(pbase + ((size_t)((iq0 + 1) * 16 + (o & 15))) * 8) = *(uint4*)v1;
    } else if (bx < 2104) {
        int base = (bx - 2088) * 8192 + t * 32;
        #pragma unroll
        for (int g = 0; g < 4; ++g) {
            const float4* s4 = (const float4*)(x + base + g * 8);
            float4 a = s4[0], b = s4[1];
            unsigned int vv[4] = { pack2(a.x, a.y), pack2(a.z, a.w),
                                   pack2(b.x, b.y), pack2(b.z, b.w) };
            *(uint4*)(g_xbf + base + g * 8) = *(uint4*)vv;
        }
    } else {
        __shared__ float c[2][COND_DIM];
        int bb = t >> 7, k = t & 127;
        int b  = (bx - 2104) * 2 + bb;
        c[bb][k] = cond[b * COND_DIM + k];
        __syncthreads();
        float acc = b1[k];
        #pragma unroll 8
        for (int i = 0; i < COND_DIM; ++i)
            acc += c[bb][i] * w1[i * HIDDEN + k];
        acc = fmaxf(acc, 0.0f);
        g_h[b * H_STRIDE + k] = acc;
        g_hbf[b * HIDDEN + k] = f2bf(acc);
        if (k < 4) g_h[b * H_STRIDE + 128 + k] = 1.0f;
    }
}

// ---------------- main: register GEMM, ring-3 pipelined B-frag loads ------
// Block: 64x64 out tile, 4 waves 2x2. A frags in VGPR (loaded once).
// Step = (plane, 64-k slab): 4 linear 1KB B loads + 8 MFMA. Ring of 3
// stage buffers, prefetch depth 2 -> 8 loads in flight vs ~250cyc L2 latency.
template<int NPL, int NSL>
static __device__ __forceinline__ void run_gemm(
    int p0, const unsigned short* __restrict__ asrc, int astride,
    const unsigned short* __restrict__ wt, unsigned short* __restrict__ slices,
    int chunk, int b0, int o0, int t, const float* __restrict__ h_s)
{
    const int lane = t & 63, wave = t >> 6;
    const int wm = wave >> 1, wn = wave & 1;
    const int qg = lane >> 4, ncol = lane & 15;

    // A fragments (registers, whole block's K)
    bf16x8 xf[NSL][2][2];
    #pragma unroll
    for (int sl = 0; sl < NSL; ++sl)
        #pragma unroll
        for (int ks = 0; ks < 2; ++ks)
            #pragma unroll
            for (int mf = 0; mf < 2; ++mf)
                xf[sl][ks][mf] = *(const bf16x8*)(asrc
                    + (size_t)(b0 + wm * 32 + mf * 16 + ncol) * astride
                    + sl * 64 + ks * 32 + qg * 8);

    // B frag base: this wave's first ntile, lane-linear 16B
    const unsigned short* fb = wt
        + ((size_t)(p0 * 16 + (o0 >> 4) + wn * 2) * 8) * 512 + (size_t)lane * 8;

    constexpr int NST = NPL * NSL;
    bf16x8 bb[3][2][2];                       // ring: [stage][ks][nf]

    auto loadB = [&](int s, int ring) {
        const int pl = s / NSL, sl = s % NSL;
        #pragma unroll
        for (int ks = 0; ks < 2; ++ks)
            #pragma unroll
            for (int nf = 0; nf < 2; ++nf)
                bb[ring][ks][nf] = *(const bf16x8*)(fb + (size_t)pl * PLANE_SZ
                    + (size_t)(nf * 8 + sl * 2 + ks) * 512);
    };

    loadB(0, 0);
    if (NST > 1) loadB(1, 1);

    f32x4 acc[2][2] = {};
    f32x4 pacc[2][2];
    float hv[2][4];

    #pragma unroll
    for (int s = 0; s < NST; ++s) {
        const int pl = s / NSL, sl = s % NSL, ring = s % 3;
        if (s + 2 < NST) loadB(s + 2, (s + 2) % 3);

        if (sl == 0) {
            #pragma unroll
            for (int mf = 0; mf < 2; ++mf)
                #pragma unroll
                for (int r = 0; r < 4; ++r)
                    hv[mf][r] = h_s[(wm * 32 + mf * 16 + qg * 4 + r) * 4 + pl];
        }

        #pragma unroll
        for (int ks = 0; ks < 2; ++ks)
            #pragma unroll
            for (int mf = 0; mf < 2; ++mf)
                #pragma unroll
                for (int nf = 0; nf < 2; ++nf) {
                    f32x4 c = (sl == 0 && ks == 0) ? (f32x4){0.f, 0.f, 0.f, 0.f}
                                                   : pacc[mf][nf];
                    pacc[mf][nf] = __builtin_amdgcn_mfma_f32_16x16x32_bf16(
                        xf[sl][ks][mf], bb[ring][ks][nf], c, 0, 0, 0);
                }

        if (sl == NSL - 1) {                  // fold plane into acc, h-scaled
            #pragma unroll
            for (int mf = 0; mf < 2; ++mf)
                #pragma unroll
                for (int nf = 0; nf < 2; ++nf)
                    #pragma unroll
                    for (int r = 0; r < 4; ++r)
                        acc[mf][nf][r] += hv[mf][r] * pacc[mf][nf][r];
        }
    }

    // epilogue: bf16 slice. C/D layout: col=lane&15, row=qg*4+reg
    unsigned short* slice = slices + (size_t)chunk * OUT_ELEMS;
    #pragma unroll
    for (int mf = 0; mf < 2; ++mf)
        #pragma unroll
        for (int nf = 0; nf < 2; ++nf)
            #pragma unroll
            for (int r = 0; r < 4; ++r) {
                int row = b0 + wm * 32 + mf * 16 + qg * 4 + r;
                int col = o0 + wn * 32 + nf * 16 + ncol;
                slice[(size_t)row * OUT_DIM + col] = f2bf(acc[mf][nf][r]);
            }
}

__global__ __launch_bounds__(256, 3)
void hyper_main_kernel(const unsigned short* __restrict__ wt,
                       unsigned short* __restrict__ slices) {
    __shared__ float h_s[256];

    const int bx    = blockIdx.x;            // 34 * 32
    const int chunk = bx >> 5;
    const int rem   = bx & 31;
    const int b0    = (rem >> 2) * 64;
    const int o0    = (rem & 3) * 64;
    const int t     = threadIdx.x;

    const int p0 = (chunk < 32) ? chunk * 4 : (chunk == 32 ? 128 : 130);

    h_s[t] = g_h[(b0 + (t >> 2)) * H_STRIDE + p0 + (t & 3)];
    __syncthreads();

    if (chunk < 32)
        run_gemm<4, 4>(p0, g_xbf, IN_DIM, wt, slices, chunk, b0, o0, t, h_s);
    else if (chunk == 32)
        run_gemm<2, 4>(p0, g_xbf, IN_DIM, wt, slices, chunk, b0, o0, t, h_s);
    else
        run_gemm<1, 2>(p0, g_hbf, HIDDEN, wt, slices, chunk, b0, o0, t, h_s);
}

// ---------------- reduce: sum bf16 slices + bias vectors -------------------
__global__ void hyper_reduce_kernel(const unsigned short* __restrict__ slices,
                                    const float* __restrict__ base_bias,
                                    const float* __restrict__ b2,
                                    float* __restrict__ out) {
    int i = blockIdx.x * 256 + threadIdx.x;        // float4 index, 32768 total
    int o = (i & 63) * 4;
    float4 bb = *(const float4*)(base_bias + o);
    float4 c2 = *(const float4*)(b2 + 65536 + o);
    float4 a;
    a.x = bb.x + c2.x; a.y = bb.y + c2.y; a.z = bb.z + c2.z; a.w = bb.w + c2.w;
    #pragma unroll
    for (int c = 0; c < NCHUNKS; ++c) {
        ushort4 v = *(const ushort4*)(slices + (size_t)c * OUT_ELEMS + (size_t)i * 4);
        a.x += bf2f(v.x); a.y += bf2f(v.y); a.z += bf2f(v.z); a.w += bf2f(v.w);
    }
    ((float4*)out)[i] = a;
}

// ---------------- launch ---------------------------------------------------
extern "C" void kernel_launch(void* const* d_in, const int* in_sizes, int n_in,
                              void* d_out, int out_size, void* d_ws, size_t ws_size,
                              hipStream_t stream) {
    const float* x           = (const float*)d_in[0];
    const float* cond        = (const float*)d_in[1];
    const float* base_weight = (const float*)d_in[2];
    const float* base_bias   = (const float*)d_in[3];
    const float* w1          = (const float*)d_in[4];
    const float* b1          = (const float*)d_in[5];
    const float* w2          = (const float*)d_in[6];
    const float* b2          = (const float*)d_in[7];
    float* out = (float*)d_out;
    unsigned short* ws = (unsigned short*)d_ws;     // 131 frag-planes + 34 slices

    hyper_prep_kernel<<<2360, 256, 0, stream>>>(x, cond, base_weight, w1, b1, w2, b2, ws);
    hyper_main_kernel<<<NCHUNKS * 32, 256, 0, stream>>>(ws, ws + SLICE_OFF);
    hyper_reduce_kernel<<<OUT_ELEMS / 4 / 256, 256, 0, stream>>>(ws + SLICE_OFF, base_bias, b2, out);
}